// Round 10
// baseline (591.682 us; speedup 1.0000x reference)
//
#include <hip/hip_runtime.h>
#include <stdint.h>

// TreeCRF sum-product BP -- DIAGNOSTIC ROUND 2.
// R8/R6 best-known bodies everywhere; the two LEAF-level kernels carry
// in-kernel repeats so their dispatches exceed the ~315us harness poison
// fills and surface in rocprof top-5 with full counters:
//   up_flat<true,8>   at d=depth  (idempotent: rewrites identical e8/mup/out)
//   down_flat<true,24> at d=depth (reps 0..22 -> ws scratch, last rep -> out)
// Read: dur/REP vs traffic floor (up ~390MB/rep, down ~170MB/rep),
// VALUBusy, hbm_gbps, FETCH -> decide BW-bound vs issue-bound for R11.

#define EPC 256   // bytes per node in e8 copy (16x16 fp8)

__device__ __forceinline__ void ldvec16(const float* p, float* d) {
    const float4* q = (const float4*)p;
    #pragma unroll
    for (int t = 0; t < 4; ++t) {
        float4 a = q[t];
        d[4*t+0] = a.x; d[4*t+1] = a.y; d[4*t+2] = a.z; d[4*t+3] = a.w;
    }
}

__device__ __forceinline__ float lse16_rs(const float* r, const float* s) {
    float v[16];
    float m;
    #pragma unroll
    for (int j = 0; j < 16; ++j) {
        v[j] = r[j] + s[j];
        m = (j == 0) ? v[0] : fmaxf(m, v[j]);
    }
    float acc = 0.f;
    #pragma unroll
    for (int j = 0; j < 16; ++j) acc += __expf(v[j] - m);
    return m + __logf(acc);
}

__device__ __forceinline__ void enc_row(uint8_t* dst, const float* E) {
    int w[4];
    #pragma unroll
    for (int t = 0; t < 4; ++t) {
        int x = __builtin_amdgcn_cvt_pk_fp8_f32(E[4*t+0], E[4*t+1], 0, false);
        x     = __builtin_amdgcn_cvt_pk_fp8_f32(E[4*t+2], E[4*t+3], x, true);
        w[t] = x;
    }
    *(int4*)dst = make_int4(w[0], w[1], w[2], w[3]);
}

__device__ __forceinline__ void dec_row(const uint8_t* src, float* E) {
    uint4 w = *(const uint4*)src;
    uint32_t a;
    a = w.x;
    E[0]  = __builtin_amdgcn_cvt_f32_fp8(a, 0);
    E[1]  = __builtin_amdgcn_cvt_f32_fp8(a, 1);
    E[2]  = __builtin_amdgcn_cvt_f32_fp8(a, 2);
    E[3]  = __builtin_amdgcn_cvt_f32_fp8(a, 3);
    a = w.y;
    E[4]  = __builtin_amdgcn_cvt_f32_fp8(a, 0);
    E[5]  = __builtin_amdgcn_cvt_f32_fp8(a, 1);
    E[6]  = __builtin_amdgcn_cvt_f32_fp8(a, 2);
    E[7]  = __builtin_amdgcn_cvt_f32_fp8(a, 3);
    a = w.z;
    E[8]  = __builtin_amdgcn_cvt_f32_fp8(a, 0);
    E[9]  = __builtin_amdgcn_cvt_f32_fp8(a, 1);
    E[10] = __builtin_amdgcn_cvt_f32_fp8(a, 2);
    E[11] = __builtin_amdgcn_cvt_f32_fp8(a, 3);
    a = w.w;
    E[12] = __builtin_amdgcn_cvt_f32_fp8(a, 0);
    E[13] = __builtin_amdgcn_cvt_f32_fp8(a, 1);
    E[14] = __builtin_amdgcn_cvt_f32_fp8(a, 2);
    E[15] = __builtin_amdgcn_cvt_f32_fp8(a, 3);
}

__device__ __forceinline__ float dec1(uint8_t b) {
    return __builtin_amdgcn_cvt_f32_fp8((uint32_t)b, 0);
}

__device__ __forceinline__ uint16_t f32_to_bf16(float x) {
    uint32_t u = __float_as_uint(x);
    u += 0x7fff + ((u >> 16) & 1);
    return (uint16_t)(u >> 16);
}
__device__ __forceinline__ float bf16_to_f32(uint16_t h) {
    return __uint_as_float((uint32_t)h << 16);
}

// ================= flat per-level kernels (R6 bodies + REP) =================
template <bool USE8, int REP>
__global__ __launch_bounds__(256) void up_flat(
    const float* __restrict__ csrc, const float* __restrict__ unary,
    const float* __restrict__ ep, float* __restrict__ out,
    uint8_t* __restrict__ e8, uint16_t* __restrict__ mup,
    int plo, int pcount) {
    int t = blockIdx.x * 256 + threadIdx.x;
    if (t >= pcount * 16) return;
    int i = t & 15;
    size_t p = (size_t)plo + (t >> 4);
    size_t cl = 2 * p + 1;

    for (int rep = 0; rep < REP; ++rep) {
        float msg[2];
        #pragma unroll
        for (int ch = 0; ch < 2; ++ch) {
            size_t c = cl + ch;
            float s[16], r[16];
            ldvec16(csrc + c * 16, s);
            ldvec16(ep + (c - 1) * 256 + i * 16, r);
            if (USE8) {
                float E[16];
                #pragma unroll
                for (int j = 0; j < 16; ++j) E[j] = __expf(r[j]);
                enc_row(e8 + (c - 1) * EPC + i * 16, E);
                float m = s[0];
                #pragma unroll
                for (int j = 1; j < 16; ++j) m = fmaxf(m, s[j]);
                float acc = 0.f;
                #pragma unroll
                for (int j = 0; j < 16; ++j) acc += E[j] * __expf(s[j] - m);
                msg[ch] = __logf(acc) + m;
                mup[c * 16 + i] = f32_to_bf16(msg[ch]);
            } else {
                msg[ch] = lse16_rs(r, s);
            }
        }
        out[p * 16 + i] = unary[p * 16 + i] + msg[0] + msg[1];
    }
}

// down_flat<USE8,REP>: reps 0..REP-2 write to scratch, last rep to out.
template <bool USE8, int REP>
__global__ __launch_bounds__(256) void down_flat(
    const float* __restrict__ ssrc, const float* __restrict__ ep,
    const uint8_t* __restrict__ e8, const uint16_t* __restrict__ mup,
    float* __restrict__ out, float* __restrict__ scratch,
    int lo, int count) {
    if (!USE8) {
        int t = blockIdx.x * 256 + threadIdx.x;
        if (t >= count * 16) return;
        int i = t & 15;
        size_t v = (size_t)lo + (t >> 4);
        size_t par = (v - 1) >> 1;
        float s[16], r[16];
        ldvec16(ssrc + v * 16, s);
        float sub_i = ssrc[v * 16 + i];
        ldvec16(ep + (v - 1) * 256 + i * 16, r);
        float mu = lse16_rs(r, s);
        float v2f = out[par * 16 + i] - mu;
        const float* nb = ep + (v - 1) * 256 + i;
        float c[16];
        #pragma unroll
        for (int k = 0; k < 16; ++k) c[k] = nb[k * 16];
        float vv[16], m;
        #pragma unroll
        for (int k = 0; k < 16; ++k) {
            float x = c[k] + __shfl(v2f, k, 16);
            vv[k] = x;
            m = (k == 0) ? x : fmaxf(m, x);
        }
        float acc = 0.f;
        #pragma unroll
        for (int k = 0; k < 16; ++k) acc += __expf(vv[k] - m);
        out[v * 16 + i] = sub_i + m + __logf(acc);
        return;
    }
    __shared__ float T[16][16][20];
    int g = threadIdx.x >> 4, i = threadIdx.x & 15;
    size_t v = (size_t)lo + (size_t)(blockIdx.x * 16 + g);
    size_t par = (v - 1) >> 1;

    for (int rep = 0; rep < REP; ++rep) {
        float* dst = (rep == REP - 1) ? out : scratch;
        float sub_i = ssrc[v * 16 + i];
        float pt    = out[par * 16 + i];
        float mu    = bf16_to_f32(mup[v * 16 + i]);
        float v2f   = pt - mu;

        float m = v2f;
        m = fmaxf(m, __shfl_xor(m, 1, 16));
        m = fmaxf(m, __shfl_xor(m, 2, 16));
        m = fmaxf(m, __shfl_xor(m, 4, 16));
        m = fmaxf(m, __shfl_xor(m, 8, 16));
        float u = __expf(v2f - m);

        float E[16];
        dec_row(e8 + (v - 1) * EPC + i * 16, E);
        #pragma unroll
        for (int j = 0; j < 16; ++j) T[g][i][j] = E[j] * u;
        __syncthreads();
        float acc = 0.f;
        #pragma unroll
        for (int k = 0; k < 16; ++k) acc += T[g][k][i];

        dst[v * 16 + i] = sub_i + __logf(acc) + m;
        __syncthreads();                 // protect T across reps
    }
}

// ================= top6: levels 1..6 up+down, one block, all-LDS =================
__global__ __launch_bounds__(1024) void top6(const float* __restrict__ unary,
                                             const float* __restrict__ ep,
                                             float* __restrict__ out) {
    __shared__ uint8_t epl[126 * 256];
    __shared__ float sb[127][16];
    __shared__ float mu[127][16];
    __shared__ float un[63][16];
    int tid = threadIdx.x;

    for (int row = tid; row < 126 * 16; row += 1024) {
        float r[16], E[16];
        ldvec16(ep + (size_t)row * 16, r);
        #pragma unroll
        for (int j = 0; j < 16; ++j) E[j] = __expf(r[j]);
        enc_row(&epl[row * 16], E);
    }
    {
        int g = tid >> 4, i = tid & 15;
        sb[63 + g][i] = out[(size_t)(63 + g) * 16 + i];
    }
    if (tid < 63 * 16) un[tid >> 4][tid & 15] = unary[tid];
    __syncthreads();

    #pragma unroll
    for (int d = 6; d >= 1; --d) {
        int pcount = 1 << (d - 1);
        if (tid < pcount * 16) {
            int pl = tid >> 4, i = tid & 15;
            int p = pcount - 1 + pl;
            float msg[2];
            #pragma unroll
            for (int ch = 0; ch < 2; ++ch) {
                int c = 2 * p + 1 + ch;
                float E[16], s[16];
                dec_row(&epl[(c - 1) * 256 + i * 16], E);
                ldvec16(&sb[c][0], s);
                float m = s[0];
                #pragma unroll
                for (int j = 1; j < 16; ++j) m = fmaxf(m, s[j]);
                float acc = 0.f;
                #pragma unroll
                for (int j = 0; j < 16; ++j) acc += E[j] * __expf(s[j] - m);
                msg[ch] = __logf(acc) + m;
                mu[c][i] = msg[ch];
            }
            sb[p][i] = un[p][i] + msg[0] + msg[1];
        }
        __syncthreads();
    }

    #pragma unroll
    for (int d = 1; d <= 6; ++d) {
        int count = 1 << d;
        if (tid < count * 16) {
            int vl = tid >> 4, i = tid & 15;
            int v = count - 1 + vl;
            int par = (v - 1) >> 1;
            float v2f = sb[par][i] - mu[v][i];
            float m = v2f;
            m = fmaxf(m, __shfl_xor(m, 1, 16));
            m = fmaxf(m, __shfl_xor(m, 2, 16));
            m = fmaxf(m, __shfl_xor(m, 4, 16));
            m = fmaxf(m, __shfl_xor(m, 8, 16));
            float u = __expf(v2f - m);
            const uint8_t* nb = &epl[(v - 1) * 256];
            float acc = 0.f;
            #pragma unroll
            for (int k = 0; k < 16; ++k)
                acc += dec1(nb[k * 16 + i]) * __shfl(u, k, 16);
            float bel = sb[v][i] + __logf(acc) + m;
            sb[v][i] = bel;
        }
        __syncthreads();
    }

    const float* sbf = &sb[0][0];
    for (int t = tid; t < 127 * 16; t += 1024) out[t] = sbf[t];
}

// ================= fused top (fp32, generic fallback only) =================
__device__ __forceinline__ void up_body_f32(const float* __restrict__ unary,
                                            const float* __restrict__ ep,
                                            float* out, size_t p, int i) {
    size_t cl = 2 * p + 1, cr = cl + 1;
    float s[16], r[16];
    ldvec16(out + cl * 16, s);
    ldvec16(ep + (cl - 1) * 256 + i * 16, r);
    float msgL = lse16_rs(r, s);
    ldvec16(out + cr * 16, s);
    ldvec16(ep + (cr - 1) * 256 + i * 16, r);
    float msgR = lse16_rs(r, s);
    out[p * 16 + i] = unary[p * 16 + i] + msgL + msgR;
}

__device__ __forceinline__ void down_body_f32(const float* __restrict__ ep,
                                              float* out, size_t v, int i) {
    size_t par = (v - 1) >> 1;
    float s[16], r[16];
    ldvec16(out + v * 16, s);
    float sub_i = out[v * 16 + i];
    ldvec16(ep + (v - 1) * 256 + i * 16, r);
    float mu = lse16_rs(r, s);
    float v2f = out[par * 16 + i] - mu;
    const float* nb = ep + (v - 1) * 256 + i;
    float c[16];
    #pragma unroll
    for (int k = 0; k < 16; ++k) c[k] = nb[k * 16];
    float vv[16], m;
    #pragma unroll
    for (int k = 0; k < 16; ++k) {
        float x = c[k] + __shfl(v2f, k, 16);
        vv[k] = x;
        m = (k == 0) ? x : fmaxf(m, x);
    }
    float acc = 0.f;
    #pragma unroll
    for (int k = 0; k < 16; ++k) acc += __expf(vv[k] - m);
    out[v * 16 + i] = sub_i + m + __logf(acc);
}

__global__ __launch_bounds__(1024) void top_fused(const float* __restrict__ unary,
                                                  const float* __restrict__ ep,
                                                  float* out, int FD) {
    int tid = threadIdx.x;
    for (int d = FD; d >= 1; --d) {
        int pcount = 1 << (d - 1);
        size_t plo = pcount - 1;
        for (int t = tid; t < pcount * 16; t += blockDim.x)
            up_body_f32(unary, ep, out, plo + (t >> 4), t & 15);
        __syncthreads();
    }
    for (int d = 1; d <= FD; ++d) {
        int count = 1 << d;
        size_t lo = count - 1;
        for (int t = tid; t < count * 16; t += blockDim.x)
            down_body_f32(ep, out, lo + (t >> 4), t & 15);
        __syncthreads();
    }
}

extern "C" void kernel_launch(void* const* d_in, const int* in_sizes, int n_in,
                              void* d_out, int out_size, void* d_ws, size_t ws_size,
                              hipStream_t stream) {
    const float* unary = (const float*)d_in[0];
    const float* ep    = (const float*)d_in[1];
    float* out = (float*)d_out;

    int Nn = in_sizes[0] / 16;
    int depth = 0;
    while ((1 << (depth + 1)) < Nn + 1) ++depth;

    uint8_t* e8 = (uint8_t*)d_ws;
    size_t e8_bytes = (size_t)Nn * EPC;
    size_t mup_off = (e8_bytes + 255) & ~(size_t)255;
    uint16_t* mup = (uint16_t*)((uint8_t*)d_ws + mup_off);
    size_t scr_off = mup_off + (((size_t)Nn * 16 * 2 + 255) & ~(size_t)255);
    float* scratch = (float*)((uint8_t*)d_ws + scr_off);
    size_t need = scr_off + (size_t)Nn * 16 * 4;
    bool use8 = ws_size >= need;

    if (use8 && depth >= 13) {
        for (int d = depth; d >= 7; --d) {
            int pcount = 1 << (d - 1);
            const float* csrc = (d == depth) ? unary : out;
            if (d == depth)
                up_flat<true, 8><<<pcount * 16 / 256, 256, 0, stream>>>(
                    csrc, unary, ep, out, e8, mup, pcount - 1, pcount);
            else
                up_flat<true, 1><<<pcount * 16 / 256, 256, 0, stream>>>(
                    csrc, unary, ep, out, e8, mup, pcount - 1, pcount);
        }
        top6<<<1, 1024, 0, stream>>>(unary, ep, out);
        for (int d = 7; d <= depth; ++d) {
            int count = 1 << d;
            const float* ssrc = (d == depth) ? unary : out;
            if (d == depth)
                down_flat<true, 24><<<count * 16 / 256, 256, 0, stream>>>(
                    ssrc, ep, e8, mup, out, scratch, count - 1, count);
            else
                down_flat<true, 1><<<count * 16 / 256, 256, 0, stream>>>(
                    ssrc, ep, e8, mup, out, scratch, count - 1, count);
        }
    } else {
        int FD = (depth >= 2) ? ((depth - 1 < 6) ? depth - 1 : 6) : 0;
        for (int d = depth; d > FD; --d) {
            int pcount = 1 << (d - 1);
            int plo = pcount - 1;
            const float* csrc = (d == depth) ? unary : out;
            dim3 grid((pcount * 16 + 255) / 256);
            up_flat<false, 1><<<grid, 256, 0, stream>>>(
                csrc, unary, ep, out, e8, mup, plo, pcount);
        }
        if (FD > 0)
            top_fused<<<1, 1024, 0, stream>>>(unary, ep, out, FD);
        for (int d = FD + 1; d <= depth; ++d) {
            int count = 1 << d;
            int lo = count - 1;
            const float* ssrc = (d == depth) ? unary : out;
            dim3 grid((count * 16 + 255) / 256);
            down_flat<false, 1><<<grid, 256, 0, stream>>>(
                ssrc, ep, e8, mup, out, scratch, lo, count);
        }
    }
}

// Round 11
// 253.018 us; speedup vs baseline: 2.3385x; 2.3385x over previous
//
#include <hip/hip_runtime.h>
#include <stdint.h>

// TreeCRF sum-product BP -- DIAGNOSTIC ROUND 3 (surface the UP kernel).
//   up_flat<true,16> at d=depth (idempotent: rewrites identical e8/mup/out);
//   REP=1 everywhere else. down_flat carries the T group-stride bank fix
//   (320 -> 325 floats: 4-way read conflict -> free 2-way).
// Pre-committed reads on the up_flat top-5 rows:
//   hbm>=5.5TB/s -> BW-bound (accept ~250us; polish);
//   hbm<=3.5 & VALU>=60% -> trans-bound -> log-domain e8 restructure;
//   occupancy<50% -> latency-bound.

#define EPC 256   // bytes per node in e8 copy (16x16 fp8)

__device__ __forceinline__ void ldvec16(const float* p, float* d) {
    const float4* q = (const float4*)p;
    #pragma unroll
    for (int t = 0; t < 4; ++t) {
        float4 a = q[t];
        d[4*t+0] = a.x; d[4*t+1] = a.y; d[4*t+2] = a.z; d[4*t+3] = a.w;
    }
}

__device__ __forceinline__ float lse16_rs(const float* r, const float* s) {
    float v[16];
    float m;
    #pragma unroll
    for (int j = 0; j < 16; ++j) {
        v[j] = r[j] + s[j];
        m = (j == 0) ? v[0] : fmaxf(m, v[j]);
    }
    float acc = 0.f;
    #pragma unroll
    for (int j = 0; j < 16; ++j) acc += __expf(v[j] - m);
    return m + __logf(acc);
}

__device__ __forceinline__ void enc_row(uint8_t* dst, const float* E) {
    int w[4];
    #pragma unroll
    for (int t = 0; t < 4; ++t) {
        int x = __builtin_amdgcn_cvt_pk_fp8_f32(E[4*t+0], E[4*t+1], 0, false);
        x     = __builtin_amdgcn_cvt_pk_fp8_f32(E[4*t+2], E[4*t+3], x, true);
        w[t] = x;
    }
    *(int4*)dst = make_int4(w[0], w[1], w[2], w[3]);
}

__device__ __forceinline__ void dec_row(const uint8_t* src, float* E) {
    uint4 w = *(const uint4*)src;
    uint32_t a;
    a = w.x;
    E[0]  = __builtin_amdgcn_cvt_f32_fp8(a, 0);
    E[1]  = __builtin_amdgcn_cvt_f32_fp8(a, 1);
    E[2]  = __builtin_amdgcn_cvt_f32_fp8(a, 2);
    E[3]  = __builtin_amdgcn_cvt_f32_fp8(a, 3);
    a = w.y;
    E[4]  = __builtin_amdgcn_cvt_f32_fp8(a, 0);
    E[5]  = __builtin_amdgcn_cvt_f32_fp8(a, 1);
    E[6]  = __builtin_amdgcn_cvt_f32_fp8(a, 2);
    E[7]  = __builtin_amdgcn_cvt_f32_fp8(a, 3);
    a = w.z;
    E[8]  = __builtin_amdgcn_cvt_f32_fp8(a, 0);
    E[9]  = __builtin_amdgcn_cvt_f32_fp8(a, 1);
    E[10] = __builtin_amdgcn_cvt_f32_fp8(a, 2);
    E[11] = __builtin_amdgcn_cvt_f32_fp8(a, 3);
    a = w.w;
    E[12] = __builtin_amdgcn_cvt_f32_fp8(a, 0);
    E[13] = __builtin_amdgcn_cvt_f32_fp8(a, 1);
    E[14] = __builtin_amdgcn_cvt_f32_fp8(a, 2);
    E[15] = __builtin_amdgcn_cvt_f32_fp8(a, 3);
}

__device__ __forceinline__ float dec1(uint8_t b) {
    return __builtin_amdgcn_cvt_f32_fp8((uint32_t)b, 0);
}

__device__ __forceinline__ uint16_t f32_to_bf16(float x) {
    uint32_t u = __float_as_uint(x);
    u += 0x7fff + ((u >> 16) & 1);
    return (uint16_t)(u >> 16);
}
__device__ __forceinline__ float bf16_to_f32(uint16_t h) {
    return __uint_as_float((uint32_t)h << 16);
}

// ================= flat per-level kernels =================
template <bool USE8, int REP>
__global__ __launch_bounds__(256) void up_flat(
    const float* __restrict__ csrc, const float* __restrict__ unary,
    const float* __restrict__ ep, float* __restrict__ out,
    uint8_t* __restrict__ e8, uint16_t* __restrict__ mup,
    int plo, int pcount) {
    int t = blockIdx.x * 256 + threadIdx.x;
    if (t >= pcount * 16) return;
    int i = t & 15;
    size_t p = (size_t)plo + (t >> 4);
    size_t cl = 2 * p + 1;

    for (int rep = 0; rep < REP; ++rep) {
        float msg[2];
        #pragma unroll
        for (int ch = 0; ch < 2; ++ch) {
            size_t c = cl + ch;
            float s[16], r[16];
            ldvec16(csrc + c * 16, s);
            ldvec16(ep + (c - 1) * 256 + i * 16, r);
            if (USE8) {
                float E[16];
                #pragma unroll
                for (int j = 0; j < 16; ++j) E[j] = __expf(r[j]);
                enc_row(e8 + (c - 1) * EPC + i * 16, E);
                float m = s[0];
                #pragma unroll
                for (int j = 1; j < 16; ++j) m = fmaxf(m, s[j]);
                float acc = 0.f;
                #pragma unroll
                for (int j = 0; j < 16; ++j) acc += E[j] * __expf(s[j] - m);
                msg[ch] = __logf(acc) + m;
                mup[c * 16 + i] = f32_to_bf16(msg[ch]);
            } else {
                msg[ch] = lse16_rs(r, s);
            }
        }
        out[p * 16 + i] = unary[p * 16 + i] + msg[0] + msg[1];
    }
}

// down_flat: node level d (lo..lo+count). USE8: exp-domain with stored E/mup;
// LDS 16x16 transpose-sum, group stride 325 (bank-conflict-free: 325%32=5).
template <bool USE8>
__global__ __launch_bounds__(256) void down_flat(
    const float* __restrict__ ssrc, const float* __restrict__ ep,
    const uint8_t* __restrict__ e8, const uint16_t* __restrict__ mup,
    float* __restrict__ out, int lo, int count) {
    if (!USE8) {
        int t = blockIdx.x * 256 + threadIdx.x;
        if (t >= count * 16) return;
        int i = t & 15;
        size_t v = (size_t)lo + (t >> 4);
        size_t par = (v - 1) >> 1;
        float s[16], r[16];
        ldvec16(ssrc + v * 16, s);
        float sub_i = ssrc[v * 16 + i];
        ldvec16(ep + (v - 1) * 256 + i * 16, r);
        float mu = lse16_rs(r, s);
        float v2f = out[par * 16 + i] - mu;
        const float* nb = ep + (v - 1) * 256 + i;
        float c[16];
        #pragma unroll
        for (int k = 0; k < 16; ++k) c[k] = nb[k * 16];
        float vv[16], m;
        #pragma unroll
        for (int k = 0; k < 16; ++k) {
            float x = c[k] + __shfl(v2f, k, 16);
            vv[k] = x;
            m = (k == 0) ? x : fmaxf(m, x);
        }
        float acc = 0.f;
        #pragma unroll
        for (int k = 0; k < 16; ++k) acc += __expf(vv[k] - m);
        out[v * 16 + i] = sub_i + m + __logf(acc);
        return;
    }
    // USE8 path: requires count*16 % 256 == 0 (levels >= 4).
    __shared__ float T[16 * 325];       // group stride 325: 4-way -> 2-way free
    int g = threadIdx.x >> 4, i = threadIdx.x & 15;
    float* Tg = &T[g * 325];
    size_t v = (size_t)lo + (size_t)(blockIdx.x * 16 + g);
    size_t par = (v - 1) >> 1;

    float sub_i = ssrc[v * 16 + i];
    float pt    = out[par * 16 + i];
    float mu    = bf16_to_f32(mup[v * 16 + i]);
    float v2f   = pt - mu;

    float m = v2f;
    m = fmaxf(m, __shfl_xor(m, 1, 16));
    m = fmaxf(m, __shfl_xor(m, 2, 16));
    m = fmaxf(m, __shfl_xor(m, 4, 16));
    m = fmaxf(m, __shfl_xor(m, 8, 16));
    float u = __expf(v2f - m);

    float E[16];
    dec_row(e8 + (v - 1) * EPC + i * 16, E);
    #pragma unroll
    for (int j = 0; j < 16; ++j) Tg[i * 20 + j] = E[j] * u;
    __syncthreads();
    float acc = 0.f;
    #pragma unroll
    for (int k = 0; k < 16; ++k) acc += Tg[k * 20 + i];

    out[v * 16 + i] = sub_i + __logf(acc) + m;
}

// ================= top6: levels 1..6 up+down, one block, all-LDS =================
__global__ __launch_bounds__(1024) void top6(const float* __restrict__ unary,
                                             const float* __restrict__ ep,
                                             float* __restrict__ out) {
    __shared__ uint8_t epl[126 * 256];
    __shared__ float sb[127][16];
    __shared__ float mu[127][16];
    __shared__ float un[63][16];
    int tid = threadIdx.x;

    for (int row = tid; row < 126 * 16; row += 1024) {
        float r[16], E[16];
        ldvec16(ep + (size_t)row * 16, r);
        #pragma unroll
        for (int j = 0; j < 16; ++j) E[j] = __expf(r[j]);
        enc_row(&epl[row * 16], E);
    }
    {
        int g = tid >> 4, i = tid & 15;
        sb[63 + g][i] = out[(size_t)(63 + g) * 16 + i];
    }
    if (tid < 63 * 16) un[tid >> 4][tid & 15] = unary[tid];
    __syncthreads();

    #pragma unroll
    for (int d = 6; d >= 1; --d) {
        int pcount = 1 << (d - 1);
        if (tid < pcount * 16) {
            int pl = tid >> 4, i = tid & 15;
            int p = pcount - 1 + pl;
            float msg[2];
            #pragma unroll
            for (int ch = 0; ch < 2; ++ch) {
                int c = 2 * p + 1 + ch;
                float E[16], s[16];
                dec_row(&epl[(c - 1) * 256 + i * 16], E);
                ldvec16(&sb[c][0], s);
                float m = s[0];
                #pragma unroll
                for (int j = 1; j < 16; ++j) m = fmaxf(m, s[j]);
                float acc = 0.f;
                #pragma unroll
                for (int j = 0; j < 16; ++j) acc += E[j] * __expf(s[j] - m);
                msg[ch] = __logf(acc) + m;
                mu[c][i] = msg[ch];
            }
            sb[p][i] = un[p][i] + msg[0] + msg[1];
        }
        __syncthreads();
    }

    #pragma unroll
    for (int d = 1; d <= 6; ++d) {
        int count = 1 << d;
        if (tid < count * 16) {
            int vl = tid >> 4, i = tid & 15;
            int v = count - 1 + vl;
            int par = (v - 1) >> 1;
            float v2f = sb[par][i] - mu[v][i];
            float m = v2f;
            m = fmaxf(m, __shfl_xor(m, 1, 16));
            m = fmaxf(m, __shfl_xor(m, 2, 16));
            m = fmaxf(m, __shfl_xor(m, 4, 16));
            m = fmaxf(m, __shfl_xor(m, 8, 16));
            float u = __expf(v2f - m);
            const uint8_t* nb = &epl[(v - 1) * 256];
            float acc = 0.f;
            #pragma unroll
            for (int k = 0; k < 16; ++k)
                acc += dec1(nb[k * 16 + i]) * __shfl(u, k, 16);
            float bel = sb[v][i] + __logf(acc) + m;
            sb[v][i] = bel;
        }
        __syncthreads();
    }

    const float* sbf = &sb[0][0];
    for (int t = tid; t < 127 * 16; t += 1024) out[t] = sbf[t];
}

// ================= fused top (fp32, generic fallback only) =================
__device__ __forceinline__ void up_body_f32(const float* __restrict__ unary,
                                            const float* __restrict__ ep,
                                            float* out, size_t p, int i) {
    size_t cl = 2 * p + 1, cr = cl + 1;
    float s[16], r[16];
    ldvec16(out + cl * 16, s);
    ldvec16(ep + (cl - 1) * 256 + i * 16, r);
    float msgL = lse16_rs(r, s);
    ldvec16(out + cr * 16, s);
    ldvec16(ep + (cr - 1) * 256 + i * 16, r);
    float msgR = lse16_rs(r, s);
    out[p * 16 + i] = unary[p * 16 + i] + msgL + msgR;
}

__device__ __forceinline__ void down_body_f32(const float* __restrict__ ep,
                                              float* out, size_t v, int i) {
    size_t par = (v - 1) >> 1;
    float s[16], r[16];
    ldvec16(out + v * 16, s);
    float sub_i = out[v * 16 + i];
    ldvec16(ep + (v - 1) * 256 + i * 16, r);
    float mu = lse16_rs(r, s);
    float v2f = out[par * 16 + i] - mu;
    const float* nb = ep + (v - 1) * 256 + i;
    float c[16];
    #pragma unroll
    for (int k = 0; k < 16; ++k) c[k] = nb[k * 16];
    float vv[16], m;
    #pragma unroll
    for (int k = 0; k < 16; ++k) {
        float x = c[k] + __shfl(v2f, k, 16);
        vv[k] = x;
        m = (k == 0) ? x : fmaxf(m, x);
    }
    float acc = 0.f;
    #pragma unroll
    for (int k = 0; k < 16; ++k) acc += __expf(vv[k] - m);
    out[v * 16 + i] = sub_i + m + __logf(acc);
}

__global__ __launch_bounds__(1024) void top_fused(const float* __restrict__ unary,
                                                  const float* __restrict__ ep,
                                                  float* out, int FD) {
    int tid = threadIdx.x;
    for (int d = FD; d >= 1; --d) {
        int pcount = 1 << (d - 1);
        size_t plo = pcount - 1;
        for (int t = tid; t < pcount * 16; t += blockDim.x)
            up_body_f32(unary, ep, out, plo + (t >> 4), t & 15);
        __syncthreads();
    }
    for (int d = 1; d <= FD; ++d) {
        int count = 1 << d;
        size_t lo = count - 1;
        for (int t = tid; t < count * 16; t += blockDim.x)
            down_body_f32(ep, out, lo + (t >> 4), t & 15);
        __syncthreads();
    }
}

extern "C" void kernel_launch(void* const* d_in, const int* in_sizes, int n_in,
                              void* d_out, int out_size, void* d_ws, size_t ws_size,
                              hipStream_t stream) {
    const float* unary = (const float*)d_in[0];
    const float* ep    = (const float*)d_in[1];
    float* out = (float*)d_out;

    int Nn = in_sizes[0] / 16;
    int depth = 0;
    while ((1 << (depth + 1)) < Nn + 1) ++depth;

    uint8_t* e8 = (uint8_t*)d_ws;
    size_t e8_bytes = (size_t)Nn * EPC;
    size_t mup_off = (e8_bytes + 255) & ~(size_t)255;
    uint16_t* mup = (uint16_t*)((uint8_t*)d_ws + mup_off);
    size_t need = mup_off + (size_t)Nn * 16 * 2;
    bool use8 = ws_size >= need;

    if (use8 && depth >= 13) {
        for (int d = depth; d >= 7; --d) {
            int pcount = 1 << (d - 1);
            const float* csrc = (d == depth) ? unary : out;
            if (d == depth)
                up_flat<true, 16><<<pcount * 16 / 256, 256, 0, stream>>>(
                    csrc, unary, ep, out, e8, mup, pcount - 1, pcount);
            else
                up_flat<true, 1><<<pcount * 16 / 256, 256, 0, stream>>>(
                    csrc, unary, ep, out, e8, mup, pcount - 1, pcount);
        }
        top6<<<1, 1024, 0, stream>>>(unary, ep, out);
        for (int d = 7; d <= depth; ++d) {
            int count = 1 << d;
            const float* ssrc = (d == depth) ? unary : out;
            down_flat<true><<<count * 16 / 256, 256, 0, stream>>>(
                ssrc, ep, e8, mup, out, count - 1, count);
        }
    } else {
        int FD = (depth >= 2) ? ((depth - 1 < 6) ? depth - 1 : 6) : 0;
        for (int d = depth; d > FD; --d) {
            int pcount = 1 << (d - 1);
            int plo = pcount - 1;
            const float* csrc = (d == depth) ? unary : out;
            dim3 grid((pcount * 16 + 255) / 256);
            up_flat<false, 1><<<grid, 256, 0, stream>>>(
                csrc, unary, ep, out, e8, mup, plo, pcount);
        }
        if (FD > 0)
            top_fused<<<1, 1024, 0, stream>>>(unary, ep, out, FD);
        for (int d = FD + 1; d <= depth; ++d) {
            int count = 1 << d;
            int lo = count - 1;
            const float* ssrc = (d == depth) ? unary : out;
            dim3 grid((count * 16 + 255) / 256);
            down_flat<false><<<grid, 256, 0, stream>>>(
                ssrc, ep, e8, mup, out, lo, count);
        }
    }
}